// Round 17
// baseline (448.327 us; speedup 1.0000x reference)
//
#include <hip/hip_runtime.h>
#include <math.h>

#define N_NODES 60
#define N_EDGES 1800
#define N_ETOT  1860
#define SLOPE   0.2f

// ---------------- LDS union: conv path vs gnn path (block 0) ----------------
// simg[3][32][32] unpadded (b128-aligned rows; py-group bank alias is 2-way =
// free per m136). c1 CROW=20: b128-aligned (mult of 4) AND conv1 write
// oc-stride 280 = 24 mod 32 (<=2-way). Weights in LDS: b32 broadcast/distinct.
#define CROW 20
#define CCH  (14 * CROW)         // 280
struct ConvS {
    float simg[3 * 1024];        // 3072 f
    float c1[6 * CCH];           // 1680 f
    float sw1[452], sb1[8];
    float sw2[2400], sb2[16];
    float pad[8];
};                               // ~30.6 KB
struct GnnS {
    float ea[N_ETOT];
    float alpha[N_ETOT];
    float x_in[960];
    float xl[960];
    float as_[N_NODES], ad_[N_NODES], den_[N_NODES];
    float red[256];
    unsigned char srcs[N_ETOT], dsts[N_ETOT];
    unsigned short csr[N_ETOT];
    int cnt[N_NODES], off[N_NODES + 4];
};
union SMem { ConvS c; GnnS g; };

__device__ __forceinline__ void block_reduce_sum(float v, float* red, float* out) {
    int tid = threadIdx.x;
    red[tid] = v;
    __syncthreads();
    for (int st = 128; st > 0; st >>= 1) {
        if (tid < st) red[tid] += red[tid + st];
        __syncthreads();
    }
    *out = red[0];
    __syncthreads();
}

// outb may alias x_in (reads barrier-separated from writes; R9/R11/R16-verified)
__device__ void gat_layer(GnnS& S, const float* x_in, int in_dim, int out_dim,
                          const float* W, const float* a_src, const float* a_dst,
                          const float* We, const float* a_edge, const float* bias,
                          float* xl, float* outb) {
    const int tid = threadIdx.x, nt = blockDim.x;
    for (int idx = tid; idx < N_NODES * out_dim; idx += nt) {
        int i = idx / out_dim, j = idx % out_dim;
        float s = 0.f;
        for (int k = 0; k < in_dim; ++k) s += x_in[i * in_dim + k] * W[k * out_dim + j];
        xl[idx] = s;
    }
    __syncthreads();
    for (int i = tid; i < N_NODES; i += nt) {
        float s = 0.f, d = 0.f;
        for (int j = 0; j < out_dim; ++j) {
            s += xl[i * out_dim + j] * a_src[j];
            d += xl[i * out_dim + j] * a_dst[j];
        }
        S.as_[i] = s; S.ad_[i] = d;
    }
    float ecoef = 0.f;
    for (int j = 0; j < out_dim; ++j) ecoef += We[j] * a_edge[j];
    __syncthreads();
    for (int e = tid; e < N_ETOT; e += nt) {
        float a = S.as_[S.srcs[e]] + S.ad_[S.dsts[e]] + S.ea[e] * ecoef;
        S.alpha[e] = (a >= 0.f) ? a : SLOPE * a;
    }
    __syncthreads();
    for (int d = tid; d < N_NODES; d += nt) {
        float m = -INFINITY;
        for (int k = S.off[d]; k < S.off[d + 1]; ++k) m = fmaxf(m, S.alpha[S.csr[k]]);
        float den = 0.f;
        for (int k = S.off[d]; k < S.off[d + 1]; ++k) {
            int e = S.csr[k];
            float ex = expf(S.alpha[e] - m);
            S.alpha[e] = ex;
            den += ex;
        }
        S.den_[d] = den;
    }
    __syncthreads();
    for (int idx = tid; idx < N_NODES * out_dim; idx += nt) {
        int d = idx / out_dim, j = idx % out_dim;
        float s = 0.f;
        for (int k = S.off[d]; k < S.off[d + 1]; ++k) {
            int e = S.csr[k];
            s += S.alpha[e] * xl[(int)S.srcs[e] * out_dim + j];
        }
        outb[idx] = s / S.den_[d] + bias[j];
    }
    __syncthreads();
}

__device__ void bn_relu(GnnS& S, float* v, int n) {   // in place
    const int tid = threadIdx.x, nt = blockDim.x;
    float s = 0.f;
    for (int i = tid; i < n; i += nt) s += v[i];
    float tot;
    block_reduce_sum(s, S.red, &tot);
    float avg = tot / n;
    float s2 = 0.f;
    for (int i = tid; i < n; i += nt) { float d = v[i] - avg; s2 += d * d; }
    block_reduce_sum(s2, S.red, &tot);
    float stdv = sqrtf(tot / n);
    __syncthreads();
    for (int i = tid; i < n; i += nt) v[i] = fmaxf((v[i] - avg) / stdv, 0.f);
    __syncthreads();
}

__device__ void gnn_run(GnnS& S,
    const float* node_fea, const float* edge_fea, const int* eidx,
    const float* g1w, const float* g1as, const float* g1ad,
    const float* g1we, const float* g1ae, const float* g1b,
    const float* g2w, const float* g2as, const float* g2ad,
    const float* g2we, const float* g2ae, const float* g2b,
    const float* fc1w, const float* fc1b, float* gcontrib) {
    const int tid = threadIdx.x, nt = blockDim.x;
    float s = 0.f;
    for (int e = tid; e < N_EDGES; e += nt) s += edge_fea[e];
    float tot;
    block_reduce_sum(s, S.red, &tot);
    float emean = tot / N_EDGES;
    for (int e = tid; e < N_ETOT; e += nt) {
        if (e < N_EDGES) {
            S.ea[e] = edge_fea[e];
            S.srcs[e] = (unsigned char)eidx[e];
            S.dsts[e] = (unsigned char)eidx[N_EDGES + e];
        } else {
            S.ea[e] = emean;
            S.srcs[e] = (unsigned char)(e - N_EDGES);
            S.dsts[e] = (unsigned char)(e - N_EDGES);
        }
    }
    if (tid < N_NODES) S.x_in[tid] = node_fea[tid];
    __syncthreads();
    if (tid < N_NODES) {
        int c = 0;
        for (int e = 0; e < N_ETOT; ++e) c += (S.dsts[e] == tid);
        S.cnt[tid] = c;
    }
    __syncthreads();
    if (tid == 0) {
        S.off[0] = 0;
        for (int d = 0; d < N_NODES; ++d) S.off[d + 1] = S.off[d] + S.cnt[d];
    }
    __syncthreads();
    if (tid < N_NODES) {
        int k = S.off[tid];
        for (int e = 0; e < N_ETOT; ++e)
            if (S.dsts[e] == tid) S.csr[k++] = (unsigned short)e;
    }
    __syncthreads();

    gat_layer(S, S.x_in, 1, 6, g1w, g1as, g1ad, g1we, g1ae, g1b, S.xl, S.x_in);
    bn_relu(S, S.x_in, N_NODES * 6);
    gat_layer(S, S.x_in, 6, 16, g2w, g2as, g2ad, g2we, g2ae, g2b, S.xl, S.x_in);
    bn_relu(S, S.x_in, N_NODES * 16);   // x_in[0..959] == g

    for (int j = tid; j < 512; j += nt) {
        float acc = fc1b[j];
#pragma unroll 4
        for (int k = 0; k < 960; ++k) acc += S.x_in[k] * fc1w[(size_t)k * 512 + j];
        gcontrib[j] = acc;
    }
}

// ---------------------------------------------------------------------------
// conv path: window-sharing with ALIGNED b128 LDS reads (2 instr = 8 dwords
// serving 40 FMAs vs R8's 5 b32 per 30) — attacks the measured LDS-issue
// bound (R16 arithmetic: 2625 LDS instr/wave x 5.8cy matches 406us).
// Item order (py,oc,qx), qx innermost: qx lanes hit consecutive 16B chunks
// (free), oc lanes broadcast, py groups 2-way (free). Weight b32 reads:
// oc-stride 75=11 / 150=22 mod 32 -> all-distinct banks. Pool fully in-lane.
// All arrays compile-time indexed (rule #20); ic unroll-1 bounds live set.
// relu(maxpool(x)) == maxpool(relu(x)).
// ---------------------------------------------------------------------------
__device__ void conv_path(ConvS& C, int img,
                          const float* __restrict__ pic,
                          const float* __restrict__ w1, const float* __restrict__ b1,
                          const float* __restrict__ w2, const float* __restrict__ b2,
                          float* __restrict__ p) {
    const int tid = threadIdx.x;

    // stage image (coalesced float4 -> lane-consecutive LDS) + weights
    {
        const float4* src = (const float4*)(pic + (size_t)img * 3072);
        float4* dst = (float4*)C.simg;
        for (int i = tid; i < 768; i += 256) dst[i] = src[i];
        for (int i = tid; i < 450; i += 256) C.sw1[i] = w1[i];
        if (tid < 6) C.sb1[tid] = b1[tid];
        for (int i = tid; i < 2400; i += 256) C.sw2[i] = w2[i];
        if (tid < 16) C.sb2[tid] = b2[tid];
    }
    __syncthreads();

    // ---- conv1: items (py,oc,qx) = 14*6*7 = 588; each -> 2 pooled px ----
    for (int it = tid; it < 588; it += 256) {
        int qx = it % 7, r = it / 7, oc = r % 6, py = r / 6;
        int x0 = 4 * qx, ybase = 2 * py;          // image rows ybase..ybase+5
        float bias = C.sb1[oc];
        float acc[2][4];
#pragma unroll
        for (int dy = 0; dy < 2; ++dy)
#pragma unroll
            for (int dx = 0; dx < 4; ++dx) acc[dy][dx] = bias;

#pragma unroll 1
        for (int ic = 0; ic < 3; ++ic) {
            float wr[25];
#pragma unroll
            for (int k = 0; k < 25; ++k) wr[k] = C.sw1[(oc * 3 + ic) * 25 + k];
            const float* B = &C.simg[ic * 1024 + ybase * 32 + x0];
#pragma unroll
            for (int i = 0; i < 6; ++i) {
                float4 A = *(const float4*)(B + i * 32);
                float4 Bv = *(const float4*)(B + i * 32 + 4);
                float row[8] = {A.x, A.y, A.z, A.w, Bv.x, Bv.y, Bv.z, Bv.w};
#pragma unroll
                for (int dy = 0; dy < 2; ++dy) {
                    int ky = i - dy;
                    if (ky >= 0 && ky < 5) {
#pragma unroll
                        for (int dx = 0; dx < 4; ++dx) {
                            float s = 0.f;
#pragma unroll
                            for (int kx = 0; kx < 5; ++kx)
                                s += row[dx + kx] * wr[ky * 5 + kx];
                            acc[dy][dx] += s;
                        }
                    }
                }
            }
        }
        // pool 2x2 in-lane + relu; b64-aligned pair write (chunk = qx)
        float m0 = fmaxf(fmaxf(acc[0][0], acc[0][1]), fmaxf(acc[1][0], acc[1][1]));
        float m1 = fmaxf(fmaxf(acc[0][2], acc[0][3]), fmaxf(acc[1][2], acc[1][3]));
        float2* dst = (float2*)&C.c1[oc * CCH + py * CROW + 2 * qx];
        *dst = make_float2(fmaxf(m0, 0.f), fmaxf(m1, 0.f));
    }
    __syncthreads();

    // ---- conv2: items (py,oc,g) = 5*16*3 = 240; g<2 -> 2 pooled px, g=2 -> 1 ----
    if (tid < 240) {
        int g = tid % 3, r = tid / 3, oc = r % 16, py = r / 16;
        int x0 = 4 * g, ybase = 2 * py;           // c1 rows ybase..ybase+5
        float bias = C.sb2[oc];
        float acc[2][4];
#pragma unroll
        for (int dy = 0; dy < 2; ++dy)
#pragma unroll
            for (int dx = 0; dx < 4; ++dx) acc[dy][dx] = bias;

#pragma unroll 1
        for (int ic = 0; ic < 6; ++ic) {
            float wr[25];
#pragma unroll
            for (int k = 0; k < 25; ++k) wr[k] = C.sw2[(oc * 6 + ic) * 25 + k];
            const float* B = &C.c1[ic * CCH + ybase * CROW + x0];
#pragma unroll
            for (int i = 0; i < 6; ++i) {
                float4 A = *(const float4*)(B + i * CROW);
                float4 Bv = *(const float4*)(B + i * CROW + 4);
                float row[8] = {A.x, A.y, A.z, A.w, Bv.x, Bv.y, Bv.z, Bv.w};
#pragma unroll
                for (int dy = 0; dy < 2; ++dy) {
                    int ky = i - dy;
                    if (ky >= 0 && ky < 5) {
#pragma unroll
                        for (int dx = 0; dx < 4; ++dx) {
                            float s = 0.f;
#pragma unroll
                            for (int kx = 0; kx < 5; ++kx)
                                s += row[dx + kx] * wr[ky * 5 + kx];
                            acc[dy][dx] += s;
                        }
                    }
                }
            }
        }
        float m0 = fmaxf(fmaxf(acc[0][0], acc[0][1]), fmaxf(acc[1][0], acc[1][1]));
        float m1 = fmaxf(fmaxf(acc[0][2], acc[0][3]), fmaxf(acc[1][2], acc[1][3]));
        float* prow = p + ((size_t)img * 16 + oc) * 25 + py * 5;
        prow[2 * g] = fmaxf(m0, 0.f);
        if (g < 2) prow[2 * g + 1] = fmaxf(m1, 0.f);
    }
}

// LDS ~30.6KB -> 5 blocks/CU; (256,4) -> VGPR cap 128 (R4-proven no-spill point)
__global__ void __launch_bounds__(256, 4) fused_kernel(
    const float* __restrict__ node_fea, const float* __restrict__ edge_fea,
    const int* __restrict__ eidx,
    const float* g1w, const float* g1as, const float* g1ad,
    const float* g1we, const float* g1ae, const float* g1b,
    const float* g2w, const float* g2as, const float* g2ad,
    const float* g2we, const float* g2ae, const float* g2b,
    const float* __restrict__ fc1w, const float* __restrict__ fc1b,
    float* __restrict__ gcontrib,
    const float* __restrict__ pic,
    const float* __restrict__ c1w, const float* __restrict__ c1b,
    const float* __restrict__ c2w, const float* __restrict__ c2b,
    float* __restrict__ p) {
    __shared__ SMem u;
    if (blockIdx.x == 0) {
        gnn_run(u.g, node_fea, edge_fea, eidx,
                g1w, g1as, g1ad, g1we, g1ae, g1b,
                g2w, g2as, g2ad, g2we, g2ae, g2b,
                fc1w, fc1b, gcontrib);
    } else {
        conv_path(u.c, blockIdx.x - 1, pic, c1w, c1b, c2w, c2b, p);
    }
}

// ---------------------------------------------------------------------------
// FC1: h[b,j] = relu(gcontrib[j] + sum_k p[b,k]*w2[k,j]); w2 = fc1_w[960:,:]
// ---------------------------------------------------------------------------
#define FC1_ROWS 16
__global__ void fc1_kernel(
    const float* __restrict__ p, const float* __restrict__ w,
    const float* __restrict__ gcontrib, float* __restrict__ h) {
    __shared__ float sp[FC1_ROWS * 400];
    const int tid = threadIdx.x;
    const size_t r0 = (size_t)blockIdx.x * FC1_ROWS;
    for (int i = tid; i < FC1_ROWS * 400; i += 256) sp[i] = p[r0 * 400 + i];
    __syncthreads();
    const int c0 = tid, c1 = tid + 256;
    float acc[FC1_ROWS][2];
#pragma unroll
    for (int r = 0; r < FC1_ROWS; ++r) { acc[r][0] = 0.f; acc[r][1] = 0.f; }
    for (int k = 0; k < 400; k += 4) {
        float wa0 = w[(size_t)(k + 0) * 512 + c0], wa1 = w[(size_t)(k + 0) * 512 + c1];
        float wb0 = w[(size_t)(k + 1) * 512 + c0], wb1 = w[(size_t)(k + 1) * 512 + c1];
        float wc0 = w[(size_t)(k + 2) * 512 + c0], wc1 = w[(size_t)(k + 2) * 512 + c1];
        float wd0 = w[(size_t)(k + 3) * 512 + c0], wd1 = w[(size_t)(k + 3) * 512 + c1];
#pragma unroll
        for (int r = 0; r < FC1_ROWS; ++r) {
            float4 pv = *(const float4*)&sp[r * 400 + k];
            acc[r][0] += pv.x * wa0 + pv.y * wb0 + pv.z * wc0 + pv.w * wd0;
            acc[r][1] += pv.x * wa1 + pv.y * wb1 + pv.z * wc1 + pv.w * wd1;
        }
    }
    float g0 = gcontrib[c0], g1 = gcontrib[c1];
#pragma unroll
    for (int r = 0; r < FC1_ROWS; ++r) {
        h[(r0 + r) * 512 + c0] = fmaxf(acc[r][0] + g0, 0.f);
        h[(r0 + r) * 512 + c1] = fmaxf(acc[r][1] + g1, 0.f);
    }
}

// ---------------------------------------------------------------------------
// FC2: out[b,j] = tanh(sum_k h[b,k]*fc2_w[k,j] + fc2_b[j]); one wave per row
// ---------------------------------------------------------------------------
__global__ void fc2_kernel(
    const float* __restrict__ h, const float* __restrict__ w,
    const float* __restrict__ b, float* __restrict__ out) {
    const int wave = threadIdx.x >> 6, lane = threadIdx.x & 63;
    const size_t row = (size_t)blockIdx.x * 4 + wave;
    const float* hr = h + row * 512;
    float partial[10];
#pragma unroll
    for (int j = 0; j < 10; ++j) partial[j] = 0.f;
    for (int k = lane; k < 512; k += 64) {
        float hv = hr[k];
        const float* wr = w + (size_t)k * 10;
#pragma unroll
        for (int j = 0; j < 10; ++j) partial[j] += hv * wr[j];
    }
#pragma unroll
    for (int j = 0; j < 10; ++j) {
        float v = partial[j];
        for (int sft = 32; sft > 0; sft >>= 1) v += __shfl_xor(v, sft, 64);
        partial[j] = v;
    }
    if (lane == 0) {
#pragma unroll
        for (int j = 0; j < 10; ++j)
            out[row * 10 + j] = tanhf(partial[j] + b[j]);
    }
}

extern "C" void kernel_launch(void* const* d_in, const int* in_sizes, int n_in,
                              void* d_out, int out_size, void* d_ws, size_t ws_size,
                              hipStream_t stream) {
    const float* node_fea = (const float*)d_in[0];
    const float* edge_fea = (const float*)d_in[1];
    const float* pic      = (const float*)d_in[2];
    const float* c1w = (const float*)d_in[3];
    const float* c1b = (const float*)d_in[4];
    const float* c2w = (const float*)d_in[5];
    const float* c2b = (const float*)d_in[6];
    const float* g1w  = (const float*)d_in[7];
    const float* g1as = (const float*)d_in[8];
    const float* g1ad = (const float*)d_in[9];
    const float* g1we = (const float*)d_in[10];
    const float* g1ae = (const float*)d_in[11];
    const float* g1b  = (const float*)d_in[12];
    const float* g2w  = (const float*)d_in[13];
    const float* g2as = (const float*)d_in[14];
    const float* g2ad = (const float*)d_in[15];
    const float* g2we = (const float*)d_in[16];
    const float* g2ae = (const float*)d_in[17];
    const float* g2b  = (const float*)d_in[18];
    const float* fc1w = (const float*)d_in[19];
    const float* fc1b = (const float*)d_in[20];
    const float* fc2w = (const float*)d_in[21];
    const float* fc2b = (const float*)d_in[22];
    const int*   eidx = (const int*)d_in[23];
    float* out = (float*)d_out;

    char* ws = (char*)d_ws;
    float* gcontrib = (float*)ws;                                   // 512 f
    float* p = (float*)(ws + 2048);                                 // 8192*400 f
    float* h = (float*)(ws + 2048 + (size_t)8192 * 400 * 4);        // 8192*512 f

    hipLaunchKernelGGL(fused_kernel, dim3(8193), dim3(256), 0, stream,
                       node_fea, edge_fea, eidx,
                       g1w, g1as, g1ad, g1we, g1ae, g1b,
                       g2w, g2as, g2ad, g2we, g2ae, g2b,
                       fc1w, fc1b, gcontrib,
                       pic, c1w, c1b, c2w, c2b, p);
    hipLaunchKernelGGL(fc1_kernel, dim3(8192 / FC1_ROWS), dim3(256), 0, stream,
                       p, fc1w + (size_t)960 * 512, gcontrib, h);
    hipLaunchKernelGGL(fc2_kernel, dim3(8192 / 4), dim3(256), 0, stream,
                       h, fc2w, fc2b, out);
}